// Round 5
// baseline (15439.284 us; speedup 1.0000x reference)
//
#include <hip/hip_runtime.h>
#include <hip/hip_bf16.h>

// Leaky-integrator RNN, persistent cooperative kernel, v3.
// B=256, T=2048, N_IN=256, N=512, N_OUT=64, ALPHA=0.1
//
// 16 groups (16 batch rows) x 2 blocks (256 cols) x 8 waves (32 cols).
// W_rec in VGPRs (128 regs, own-K/partner-K split, all constant-indexed).
// x-kernel B-frags in LDS (128 KiB). Own tanh-state half in padded LDS
// (stride 528B). Partner half loaded direct-to-A-fragment via system-scope
// (sc0 sc1, L1/L2-bypass) loads from a fragment-ordered IF buffer; one
// monotonic per-block flag counter, vmcnt(0)-release before atomicAdd.

#define B_SZ  256
#define T_SZ  2048
#define N_IN  256
#define N_H   512
#define N_OUT 64
#define STRIDE 264   // u16 per state row (528 B) — breaks stride-512 conflicts

typedef short bf16x8 __attribute__((ext_vector_type(8)));
typedef float f32x4  __attribute__((ext_vector_type(4)));
typedef unsigned long long u64;

union frag { bf16x8 v; u64 d[2]; unsigned int u[4]; unsigned short s[8]; };

__device__ __forceinline__ unsigned short f2bf(float f) {
    union { float f; unsigned int u; } v; v.f = f;
    v.u += 0x7fffu + ((v.u >> 16) & 1u);   // RNE
    return (unsigned short)(v.u >> 16);
}

__device__ __forceinline__ float fast_tanh(float x) {
    float t = __builtin_amdgcn_exp2f(2.885390081777927f * x);
    return 1.0f - 2.0f * __builtin_amdgcn_rcpf(t + 1.0f);
}

__device__ __forceinline__ unsigned int cvt_pk_bf16(float lo, float hi) {
    unsigned int r;
    asm("v_cvt_pk_bf16_f32 %0, %1, %2" : "=v"(r) : "v"(lo), "v"(hi));
    return r;
}

#define MFMA16(A, B, C) __builtin_amdgcn_mfma_f32_16x16x32_bf16((A), (B), (C), 0, 0, 0)

__global__ __launch_bounds__(512, 1) void rnn_persistent(
    const float* __restrict__ x,        // [B][T][N_IN]
    const float* __restrict__ wk,       // [N_IN][N_H]
    const float* __restrict__ wr,       // [N_H][N_H]
    const float* __restrict__ bias,     // [N_H]
    unsigned short* __restrict__ gbuf,  // [2][16][2][8][4][16][8] bf16 frag-ordered
    unsigned int* __restrict__ flags,   // [16][2] monotonic wave counters
    float* __restrict__ lastb)          // [B][N_H] final f32 state
{
    __shared__ unsigned short ldsK[8 * 16 * 64 * 8];  // 128 KiB: [kc][tile][lane][8]
    __shared__ unsigned short st[2 * 16 * STRIDE];    // 16.5 KiB, 2 parities

    const int tid  = threadIdx.x;
    const int lane = tid & 63;
    const int w    = tid >> 6;            // wave 0..7
    const int bid  = blockIdx.x;           // 0..31
    const int g    = bid & 15;             // group (pair {g, g+16} co-XCD by %8)
    const int h    = bid >> 4;             // col half 0/1
    const int lm   = lane & 15;
    const int lg   = lane >> 4;
    const int row0 = g * 16;
    const int colbase = h * 256;

    for (int i = tid; i < 2 * 16 * STRIDE; i += 512) st[i] = 0;

    // ---- stage x-kernel B-frags into LDS: [kc][tile][lane] 16B, conflict-free
    #pragma unroll
    for (int n = 0; n < 2; ++n) {
        int t = w * 2 + n;
        for (int kc = 0; kc < 8; ++kc) {
            frag f;
            #pragma unroll
            for (int i = 0; i < 8; ++i)
                f.s[i] = f2bf(wk[(size_t)(kc * 32 + lg * 8 + i) * N_H + colbase + t * 16 + lm]);
            *(bf16x8*)&ldsK[((kc * 16 + t) * 64 + lane) * 8] = f.v;
        }
    }

    // ---- W_rec B-frags in VGPRs: own-K chunks and partner-K chunks (const-indexed)
    bf16x8 WFo[2][8], WFp[2][8];
    #pragma unroll
    for (int n = 0; n < 2; ++n) {
        for (int kc = 0; kc < 8; ++kc) {
            frag fo, fp;
            #pragma unroll
            for (int i = 0; i < 8; ++i) {
                int col = colbase + w * 32 + n * 16 + lm;
                fo.s[i] = f2bf(wr[(size_t)((h * 8 + kc) * 32 + lg * 8 + i) * N_H + col]);
                fp.s[i] = f2bf(wr[(size_t)(((1 - h) * 8 + kc) * 32 + lg * 8 + i) * N_H + col]);
            }
            WFo[n][kc] = fo.v;
            WFp[n][kc] = fp.v;
        }
    }

    const float bc0 = 0.1f * bias[colbase + w * 32 + lm];
    const float bc1 = 0.1f * bias[colbase + w * 32 + 16 + lm];

    f32x4 prev0 = {0.f, 0.f, 0.f, 0.f};
    f32x4 prev1 = {0.f, 0.f, 0.f, 0.f};

    unsigned int* myflag = &flags[g * 2 + h];
    unsigned int* pflag  = &flags[g * 2 + (1 - h)];

    const float* xrow = x + (size_t)(row0 + lm) * T_SZ * N_IN + lg * 8;

    __syncthreads();   // ldsK + st zeros visible

    for (int s = 0; s < T_SZ; ++s) {
        const int p = s & 1, q = p ^ 1;

        // ---- A: poll partner flag (one broadcast dword) ----
        if (s > 0) {
            const unsigned int tgt = 8u * (unsigned int)s;
            while (__hip_atomic_load(pflag, __ATOMIC_RELAXED,
                                     __HIP_MEMORY_SCOPE_SYSTEM) < tgt)
                __builtin_amdgcn_s_sleep(1);
        }

        // ---- B: partner A-frag loads, direct to regs (sc1, frag-ordered) ----
        frag P[8];
        {
            const u64* pb = (const u64*)gbuf
                          + ((((size_t)p * 16 + g) * 2 + (1 - h)) * 8) * 128
                          + (lg * 16 + lm) * 2;
            #pragma unroll
            for (int kc = 0; kc < 8; ++kc) {
                P[kc].d[0] = __hip_atomic_load(pb + kc * 128,
                                 __ATOMIC_RELAXED, __HIP_MEMORY_SCOPE_SYSTEM);
                P[kc].d[1] = __hip_atomic_load(pb + kc * 128 + 1,
                                 __ATOMIC_RELAXED, __HIP_MEMORY_SCOPE_SYSTEM);
            }
        }

        // ---- C: own-K T-part from padded LDS ----
        f32x4 a0 = {0.f, 0.f, 0.f, 0.f};
        f32x4 a1 = {0.f, 0.f, 0.f, 0.f};
        const unsigned short* stp = st + p * 16 * STRIDE;
        #pragma unroll
        for (int kc = 0; kc < 8; ++kc) {
            bf16x8 a = *(const bf16x8*)(stp + lm * STRIDE + kc * 32 + lg * 8);
            a0 = MFMA16(a, WFo[0][kc], a0);
            a1 = MFMA16(a, WFo[1][kc], a1);
        }

        // ---- D: x-part (covers partner-load latency) ----
        const float* xp = xrow + (size_t)s * N_IN;
        #pragma unroll
        for (int kc = 0; kc < 8; ++kc) {
            f32x4 xa = *(const f32x4*)(xp + kc * 32);
            f32x4 xb = *(const f32x4*)(xp + kc * 32 + 4);
            frag a;
            a.u[0] = cvt_pk_bf16(xa[0], xa[1]);
            a.u[1] = cvt_pk_bf16(xa[2], xa[3]);
            a.u[2] = cvt_pk_bf16(xb[0], xb[1]);
            a.u[3] = cvt_pk_bf16(xb[2], xb[3]);
            bf16x8 b0 = *(const bf16x8*)&ldsK[((kc * 16 + w * 2) * 64 + lane) * 8];
            bf16x8 b1 = *(const bf16x8*)&ldsK[((kc * 16 + w * 2 + 1) * 64 + lane) * 8];
            a0 = MFMA16(a.v, b0, a0);
            a1 = MFMA16(a.v, b1, a1);
        }

        // ---- E: partner-K T-part (compiler waits vmcnt on P loads) ----
        #pragma unroll
        for (int kc = 0; kc < 8; ++kc) {
            a0 = MFMA16(P[kc].v, WFp[0][kc], a0);
            a1 = MFMA16(P[kc].v, WFp[1][kc], a1);
        }

        // ---- F: epilogue -> own cols of LDS[q] ----
        unsigned short* stq = st + q * 16 * STRIDE;
        #pragma unroll
        for (int n = 0; n < 2; ++n) {
            f32x4 acc = n ? a1 : a0;
            float bc  = n ? bc1 : bc0;
            #pragma unroll
            for (int r = 0; r < 4; ++r) {
                float pv = n ? prev1[r] : prev0[r];
                float ns = 0.9f * pv + 0.1f * acc[r] + bc;
                float o  = fast_tanh(ns);
                if (n) prev1[r] = o; else prev0[r] = o;
                int row = lg * 4 + r;
                stq[row * STRIDE + (w * 2 + n) * 16 + lm] = f2bf(fast_tanh(o));
                if (s == T_SZ - 1)
                    lastb[(size_t)(row0 + row) * N_H + colbase + (w * 2 + n) * 16 + lm] = o;
            }
        }
        if (s == T_SZ - 1) break;

        // ---- G: publish own 1KB slice (frag-ordered), release, count ----
        {
            frag v;
            v.v = *(const bf16x8*)(stq + lm * STRIDE + w * 32 + lg * 8);
            u64* gp = (u64*)gbuf
                    + ((((size_t)q * 16 + g) * 2 + h) * 8 + w) * 128
                    + (lg * 16 + lm) * 2;
            __hip_atomic_store(gp,     v.d[0], __ATOMIC_RELAXED, __HIP_MEMORY_SCOPE_SYSTEM);
            __hip_atomic_store(gp + 1, v.d[1], __ATOMIC_RELAXED, __HIP_MEMORY_SCOPE_SYSTEM);
            asm volatile("s_waitcnt vmcnt(0)" ::: "memory");   // data at IF before flag
            if (lane == 0)
                __hip_atomic_fetch_add(myflag, 1u, __ATOMIC_RELAXED,
                                       __HIP_MEMORY_SCOPE_SYSTEM);
        }

        __syncthreads();   // LDS[q] complete before next step's own-K reads
    }
}

__global__ void dense_kernel(const float* __restrict__ last,
                             const float* __restrict__ dw,   // [N_H][N_OUT]
                             const float* __restrict__ db,   // [N_OUT]
                             float* __restrict__ out)        // [B][N_OUT]
{
    const int b = blockIdx.x;
    const int n = threadIdx.x;
    const float* lr = last + (size_t)b * N_H;
    float acc = db[n];
    #pragma unroll 8
    for (int k = 0; k < N_H; ++k)
        acc += lr[k] * dw[(size_t)k * N_OUT + n];
    out[(size_t)b * N_OUT + n] = acc;
}

extern "C" void kernel_launch(void* const* d_in, const int* in_sizes, int n_in,
                              void* d_out, int out_size, void* d_ws, size_t ws_size,
                              hipStream_t stream) {
    const float* x    = (const float*)d_in[0];
    const float* wk   = (const float*)d_in[1];
    const float* wr   = (const float*)d_in[2];
    const float* bias = (const float*)d_in[3];
    const float* dw   = (const float*)d_in[4];
    const float* db   = (const float*)d_in[5];
    float* out = (float*)d_out;

    const size_t GBUF_BYTES = (size_t)2 * 16 * 2 * 8 * 4 * 16 * 8 * sizeof(unsigned short); // 512 KiB
    const size_t FLAG_BYTES = 16 * 2 * sizeof(unsigned int);

    unsigned short* gbuf  = (unsigned short*)d_ws;
    unsigned int*   flags = (unsigned int*)((char*)d_ws + GBUF_BYTES);
    float*          lastb = (float*)((char*)d_ws + GBUF_BYTES + FLAG_BYTES);

    hipMemsetAsync(d_ws, 0, GBUF_BYTES + FLAG_BYTES, stream);

    void* args[] = { (void*)&x, (void*)&wk, (void*)&wr, (void*)&bias,
                     (void*)&gbuf, (void*)&flags, (void*)&lastb };
    hipLaunchCooperativeKernel(reinterpret_cast<void*>(rnn_persistent),
                               dim3(32), dim3(512), args, 0, stream);

    dense_kernel<<<dim3(B_SZ), dim3(N_OUT), 0, stream>>>(lastb, dw, db, out);
}

// Round 6
// 15234.619 us; speedup vs baseline: 1.0134x; 1.0134x over previous
//
#include <hip/hip_runtime.h>
#include <hip/hip_bf16.h>

// Leaky-integrator RNN, persistent cooperative kernel, v3.
// B=256, T=2048, N_IN=256, N=512, N_OUT=64, ALPHA=0.1
//
// 16 groups (16 batch rows) x 2 blocks (256 cols) x 8 waves (32 cols).
// W_rec in VGPRs (128 regs, own-K/partner-K split, all constant-indexed).
// x-kernel B-frags in LDS (128 KiB). Own tanh-state half in padded LDS
// (stride 528B). Partner half loaded direct-to-A-fragment via system-scope
// (sc0 sc1, L1/L2-bypass) loads from a fragment-ordered IF buffer; one
// monotonic per-block flag counter, vmcnt(0)-release before atomicAdd.

#define B_SZ  256
#define T_SZ  2048
#define N_IN  256
#define N_H   512
#define N_OUT 64
#define STRIDE 264   // u16 per state row (528 B) — breaks stride-512 conflicts

typedef short bf16x8 __attribute__((ext_vector_type(8)));
typedef float f32x4  __attribute__((ext_vector_type(4)));
typedef unsigned long long u64;

union frag { bf16x8 v; u64 d[2]; unsigned int u[4]; unsigned short s[8]; };

__device__ __forceinline__ unsigned short f2bf(float f) {
    union { float f; unsigned int u; } v; v.f = f;
    v.u += 0x7fffu + ((v.u >> 16) & 1u);   // RNE
    return (unsigned short)(v.u >> 16);
}

__device__ __forceinline__ float fast_tanh(float x) {
    float t = __builtin_amdgcn_exp2f(2.885390081777927f * x);
    return 1.0f - 2.0f * __builtin_amdgcn_rcpf(t + 1.0f);
}

__device__ __forceinline__ unsigned int cvt_pk_bf16(float lo, float hi) {
    unsigned int r;
    asm("v_cvt_pk_bf16_f32 %0, %1, %2" : "=v"(r) : "v"(lo), "v"(hi));
    return r;
}

#define MFMA16(A, B, C) __builtin_amdgcn_mfma_f32_16x16x32_bf16((A), (B), (C), 0, 0, 0)

__global__ __launch_bounds__(512, 1) void rnn_persistent(
    const float* __restrict__ x,        // [B][T][N_IN]
    const float* __restrict__ wk,       // [N_IN][N_H]
    const float* __restrict__ wr,       // [N_H][N_H]
    const float* __restrict__ bias,     // [N_H]
    unsigned short* __restrict__ gbuf,  // [2][16][2][8][4][16][8] bf16 frag-ordered
    unsigned int* __restrict__ flags,   // [16][2] monotonic wave counters
    float* __restrict__ lastb)          // [B][N_H] final f32 state
{
    __shared__ unsigned short ldsK[8 * 16 * 64 * 8];  // 128 KiB: [kc][tile][lane][8]
    __shared__ unsigned short st[2 * 16 * STRIDE];    // 16.5 KiB, 2 parities

    const int tid  = threadIdx.x;
    const int lane = tid & 63;
    const int w    = tid >> 6;            // wave 0..7
    const int bid  = blockIdx.x;           // 0..31
    const int g    = bid & 15;             // group (pair {g, g+16} co-XCD by %8)
    const int h    = bid >> 4;             // col half 0/1
    const int lm   = lane & 15;
    const int lg   = lane >> 4;
    const int row0 = g * 16;
    const int colbase = h * 256;

    for (int i = tid; i < 2 * 16 * STRIDE; i += 512) st[i] = 0;

    // ---- stage x-kernel B-frags into LDS: [kc][tile][lane] 16B, conflict-free
    #pragma unroll
    for (int n = 0; n < 2; ++n) {
        int t = w * 2 + n;
        for (int kc = 0; kc < 8; ++kc) {
            frag f;
            #pragma unroll
            for (int i = 0; i < 8; ++i)
                f.s[i] = f2bf(wk[(size_t)(kc * 32 + lg * 8 + i) * N_H + colbase + t * 16 + lm]);
            *(bf16x8*)&ldsK[((kc * 16 + t) * 64 + lane) * 8] = f.v;
        }
    }

    // ---- W_rec B-frags in VGPRs: own-K chunks and partner-K chunks (const-indexed)
    bf16x8 WFo[2][8], WFp[2][8];
    #pragma unroll
    for (int n = 0; n < 2; ++n) {
        for (int kc = 0; kc < 8; ++kc) {
            frag fo, fp;
            #pragma unroll
            for (int i = 0; i < 8; ++i) {
                int col = colbase + w * 32 + n * 16 + lm;
                fo.s[i] = f2bf(wr[(size_t)((h * 8 + kc) * 32 + lg * 8 + i) * N_H + col]);
                fp.s[i] = f2bf(wr[(size_t)(((1 - h) * 8 + kc) * 32 + lg * 8 + i) * N_H + col]);
            }
            WFo[n][kc] = fo.v;
            WFp[n][kc] = fp.v;
        }
    }

    const float bc0 = 0.1f * bias[colbase + w * 32 + lm];
    const float bc1 = 0.1f * bias[colbase + w * 32 + 16 + lm];

    f32x4 prev0 = {0.f, 0.f, 0.f, 0.f};
    f32x4 prev1 = {0.f, 0.f, 0.f, 0.f};

    unsigned int* myflag = &flags[g * 2 + h];
    unsigned int* pflag  = &flags[g * 2 + (1 - h)];

    const float* xrow = x + (size_t)(row0 + lm) * T_SZ * N_IN + lg * 8;

    __syncthreads();   // ldsK + st zeros visible

    for (int s = 0; s < T_SZ; ++s) {
        const int p = s & 1, q = p ^ 1;

        // ---- A: poll partner flag (one broadcast dword) ----
        if (s > 0) {
            const unsigned int tgt = 8u * (unsigned int)s;
            while (__hip_atomic_load(pflag, __ATOMIC_RELAXED,
                                     __HIP_MEMORY_SCOPE_SYSTEM) < tgt)
                __builtin_amdgcn_s_sleep(1);
        }

        // ---- B: partner A-frag loads, direct to regs (sc1, frag-ordered) ----
        frag P[8];
        {
            const u64* pb = (const u64*)gbuf
                          + ((((size_t)p * 16 + g) * 2 + (1 - h)) * 8) * 128
                          + (lg * 16 + lm) * 2;
            #pragma unroll
            for (int kc = 0; kc < 8; ++kc) {
                P[kc].d[0] = __hip_atomic_load(pb + kc * 128,
                                 __ATOMIC_RELAXED, __HIP_MEMORY_SCOPE_SYSTEM);
                P[kc].d[1] = __hip_atomic_load(pb + kc * 128 + 1,
                                 __ATOMIC_RELAXED, __HIP_MEMORY_SCOPE_SYSTEM);
            }
        }

        // ---- C: own-K T-part from padded LDS ----
        f32x4 a0 = {0.f, 0.f, 0.f, 0.f};
        f32x4 a1 = {0.f, 0.f, 0.f, 0.f};
        const unsigned short* stp = st + p * 16 * STRIDE;
        #pragma unroll
        for (int kc = 0; kc < 8; ++kc) {
            bf16x8 a = *(const bf16x8*)(stp + lm * STRIDE + kc * 32 + lg * 8);
            a0 = MFMA16(a, WFo[0][kc], a0);
            a1 = MFMA16(a, WFo[1][kc], a1);
        }

        // ---- D: x-part (covers partner-load latency) ----
        const float* xp = xrow + (size_t)s * N_IN;
        #pragma unroll
        for (int kc = 0; kc < 8; ++kc) {
            f32x4 xa = *(const f32x4*)(xp + kc * 32);
            f32x4 xb = *(const f32x4*)(xp + kc * 32 + 4);
            frag a;
            a.u[0] = cvt_pk_bf16(xa[0], xa[1]);
            a.u[1] = cvt_pk_bf16(xa[2], xa[3]);
            a.u[2] = cvt_pk_bf16(xb[0], xb[1]);
            a.u[3] = cvt_pk_bf16(xb[2], xb[3]);
            bf16x8 b0 = *(const bf16x8*)&ldsK[((kc * 16 + w * 2) * 64 + lane) * 8];
            bf16x8 b1 = *(const bf16x8*)&ldsK[((kc * 16 + w * 2 + 1) * 64 + lane) * 8];
            a0 = MFMA16(a.v, b0, a0);
            a1 = MFMA16(a.v, b1, a1);
        }

        // ---- E: partner-K T-part (compiler waits vmcnt on P loads) ----
        #pragma unroll
        for (int kc = 0; kc < 8; ++kc) {
            a0 = MFMA16(P[kc].v, WFp[0][kc], a0);
            a1 = MFMA16(P[kc].v, WFp[1][kc], a1);
        }

        // ---- F: epilogue -> own cols of LDS[q] ----
        unsigned short* stq = st + q * 16 * STRIDE;
        #pragma unroll
        for (int n = 0; n < 2; ++n) {
            f32x4 acc = n ? a1 : a0;
            float bc  = n ? bc1 : bc0;
            #pragma unroll
            for (int r = 0; r < 4; ++r) {
                float pv = n ? prev1[r] : prev0[r];
                float ns = 0.9f * pv + 0.1f * acc[r] + bc;
                float o  = fast_tanh(ns);
                if (n) prev1[r] = o; else prev0[r] = o;
                int row = lg * 4 + r;
                stq[row * STRIDE + (w * 2 + n) * 16 + lm] = f2bf(fast_tanh(o));
                if (s == T_SZ - 1)
                    lastb[(size_t)(row0 + row) * N_H + colbase + (w * 2 + n) * 16 + lm] = o;
            }
        }
        if (s == T_SZ - 1) break;

        // ---- G: publish own 1KB slice (frag-ordered), release, count ----
        {
            frag v;
            v.v = *(const bf16x8*)(stq + lm * STRIDE + w * 32 + lg * 8);
            u64* gp = (u64*)gbuf
                    + ((((size_t)q * 16 + g) * 2 + h) * 8 + w) * 128
                    + (lg * 16 + lm) * 2;
            __hip_atomic_store(gp,     v.d[0], __ATOMIC_RELAXED, __HIP_MEMORY_SCOPE_SYSTEM);
            __hip_atomic_store(gp + 1, v.d[1], __ATOMIC_RELAXED, __HIP_MEMORY_SCOPE_SYSTEM);
            asm volatile("s_waitcnt vmcnt(0)" ::: "memory");   // data at IF before flag
            if (lane == 0)
                __hip_atomic_fetch_add(myflag, 1u, __ATOMIC_RELAXED,
                                       __HIP_MEMORY_SCOPE_SYSTEM);
        }

        __syncthreads();   // LDS[q] complete before next step's own-K reads
    }
}

__global__ void dense_kernel(const float* __restrict__ last,
                             const float* __restrict__ dw,   // [N_H][N_OUT]
                             const float* __restrict__ db,   // [N_OUT]
                             float* __restrict__ out)        // [B][N_OUT]
{
    const int b = blockIdx.x;
    const int n = threadIdx.x;
    const float* lr = last + (size_t)b * N_H;
    float acc = db[n];
    #pragma unroll 8
    for (int k = 0; k < N_H; ++k)
        acc += lr[k] * dw[(size_t)k * N_OUT + n];
    out[(size_t)b * N_OUT + n] = acc;
}

extern "C" void kernel_launch(void* const* d_in, const int* in_sizes, int n_in,
                              void* d_out, int out_size, void* d_ws, size_t ws_size,
                              hipStream_t stream) {
    const float* x    = (const float*)d_in[0];
    const float* wk   = (const float*)d_in[1];
    const float* wr   = (const float*)d_in[2];
    const float* bias = (const float*)d_in[3];
    const float* dw   = (const float*)d_in[4];
    const float* db   = (const float*)d_in[5];
    float* out = (float*)d_out;

    const size_t GBUF_BYTES = (size_t)2 * 16 * 2 * 8 * 4 * 16 * 8 * sizeof(unsigned short); // 512 KiB
    const size_t FLAG_BYTES = 16 * 2 * sizeof(unsigned int);

    unsigned short* gbuf  = (unsigned short*)d_ws;
    unsigned int*   flags = (unsigned int*)((char*)d_ws + GBUF_BYTES);
    float*          lastb = (float*)((char*)d_ws + GBUF_BYTES + FLAG_BYTES);

    hipMemsetAsync(d_ws, 0, GBUF_BYTES + FLAG_BYTES, stream);

    void* args[] = { (void*)&x, (void*)&wk, (void*)&wr, (void*)&bias,
                     (void*)&gbuf, (void*)&flags, (void*)&lastb };
    hipLaunchCooperativeKernel(reinterpret_cast<void*>(rnn_persistent),
                               dim3(32), dim3(512), args, 0, stream);

    dense_kernel<<<dim3(B_SZ), dim3(N_OUT), 0, stream>>>(lastb, dw, db, out);
}